// Round 3
// baseline (32.174 us; speedup 1.0000x reference)
//
#include <hip/hip_runtime.h>

// WICC dynamic-connectivity step, fused edge-update + scatter-add.
// B=16, D=1024, E=D*D. All f32.
// Outputs concatenated: phi_out [B*D] then edge_state_next [B*E].
//
// Round 3: same as round-2 design, with native clang vector type for the
// nontemporal builtins (HIP_vector_type structs are rejected).

#define WICC_B 16
#define WICC_D 1024

typedef float vfloat4 __attribute__((ext_vector_type(4)));

__global__ __launch_bounds__(256) void wicc_step_kernel(
    const float* __restrict__ state,     // [B, D]
    const float* __restrict__ phi,       // [B, D]
    const float* __restrict__ J,         // [D, D] (dst, src)
    const float* __restrict__ es_in,     // [B, E]
    float* __restrict__ phi_out,         // [B, D]
    float* __restrict__ es_out)          // [B, E]
{
    // 4096 blocks. Block i -> XCD (i&7) under round-robin dispatch; each XCD
    // owns a contiguous 128-dst slab (512 KB of J) for all batches.
    const int i    = blockIdx.x;          // 0..4095
    const int xcd  = i & 7;
    const int slot = i >> 3;              // 0..511
    const int bgrp = slot & 3;            // 0..3  (batch group fastest -> J row reused back-to-back)
    const int dst  = xcd * 128 + (slot >> 2);   // 0..1023

    const int wave = threadIdx.x >> 6;    // 0..3
    const int lane = threadIdx.x & 63;
    const int b    = bgrp * 4 + wave;     // all 4 waves: same dst, different b

    const vfloat4* __restrict__ jrow = reinterpret_cast<const vfloat4*>(J + (size_t)dst * WICC_D);
    const vfloat4* __restrict__ srow = reinterpret_cast<const vfloat4*>(state + (size_t)b * WICC_D);
    const size_t ebase4 = ((size_t)b * WICC_D * WICC_D + (size_t)dst * WICC_D) >> 2;
    const vfloat4* __restrict__ erow = reinterpret_cast<const vfloat4*>(es_in) + ebase4;
    vfloat4*       __restrict__ orow = reinterpret_cast<vfloat4*>(es_out) + ebase4;

    // Each lane: 16 edges as 4x float4 at stride 64 (1 KB contiguous per wave-load).
    vfloat4 j4[4], s4[4], e4[4];
    #pragma unroll
    for (int k = 0; k < 4; ++k) {
        const int idx = lane + 64 * k;
        j4[k] = jrow[idx];
        s4[k] = srow[idx];
        e4[k] = __builtin_nontemporal_load(&erow[idx]);
    }

    const float J_IN = 0.38f, GP = 1e-3f, GM = 1e-3f, BIAS = 2.0f, TH = 0.1675f;

    float acc = 0.0f;
    #pragma unroll
    for (int k = 0; k < 4; ++k) {
        vfloat4 o4;
        #pragma unroll
        for (int c = 0; c < 4; ++c) {
            const float x  = s4[k][c] * J_IN;
            const float jj = j4[k][c];
            const float es = e4[k][c];
            const float pa = x + jj;
            const float pb = x - jj;
            const float ca = BIAS - es;
            const float cb = BIAS + es;
            const float ra = sqrtf(fmaxf(ca * ca - 1.0f, 0.0f));
            const float rb = sqrtf(fmaxf(cb * cb - 1.0f, 0.0f));
            const float ga = (fabsf(pa) > TH) ? ra : 0.0f;
            const float gb = (fabsf(pb) > TH) ? rb : 0.0f;
            const float esn = es + (GP * (ga - gb) - GM * es);   // DT = 1
            o4[c] = esn;
            acc += esn;
        }
        __builtin_nontemporal_store(o4, &orow[lane + 64 * k]);
    }

    // Wave-level row-sum (no LDS, no barrier).
    #pragma unroll
    for (int off = 32; off > 0; off >>= 1)
        acc += __shfl_down(acc, off, 64);

    if (lane == 0) {
        const int node = b * WICC_D + dst;
        phi_out[node] = phi[node] + 0.38f * acc;   // J_OUT = 0.38
    }
}

extern "C" void kernel_launch(void* const* d_in, const int* in_sizes, int n_in,
                              void* d_out, int out_size, void* d_ws, size_t ws_size,
                              hipStream_t stream) {
    const float* state = (const float*)d_in[0];   // [B, D]
    const float* phi   = (const float*)d_in[1];   // [B, D]
    const float* J     = (const float*)d_in[2];   // [D, D]
    const float* es    = (const float*)d_in[3];   // [B, E]

    float* phi_out = (float*)d_out;                         // [B*D]
    float* es_out  = (float*)d_out + WICC_B * WICC_D;       // [B*E]

    wicc_step_kernel<<<dim3(WICC_D * (WICC_B / 4)), dim3(256), 0, stream>>>(
        state, phi, J, es, phi_out, es_out);
}